// Round 7
// baseline (330.709 us; speedup 1.0000x reference)
//
#include <hip/hip_runtime.h>
#include <hip/hip_bf16.h>
#include <math.h>

// ---------------------------------------------------------------------------
// GraphSAGE (3-layer, mean aggr), N=100000, E=1600000.
// mean_agg(x) @ W == mean_agg(x @ W): GEMMs first, aggregate narrow messages.
// R6->R7: agg_relu unrolled to 8 pairs (8 y-gathers in flight per wave before
// any accumulate; deg-16 mode completes in ONE unrolled block), (offs,deg)
// packed into one int2 load, zero_i replaced by hipMemsetAsync, prep_w folded
// into hist_bucket's grid. Shfl-safe pair region widened 28->32.
// All __shfl executed under full exec (R5's divergent-shfl bug stays fixed).
// CSR build via two-level counting sort (R2, unchanged).
// ---------------------------------------------------------------------------

#define SHIFT 7
#define BKT 128
#define CHUNK 4096

typedef __bf16 bf16_t;
typedef bf16_t bf16x8 __attribute__((ext_vector_type(8)));
typedef float f32x4 __attribute__((ext_vector_type(4)));

// ---- pass A1: histogram of dst>>SHIFT; extra blocks do the weight prep ----
__global__ __launch_bounds__(256) void hist_bucket(const int* __restrict__ dstv,
                                                   int* __restrict__ bucket_cnt,
                                                   int E, int NB, int nbC,
                                                   const float* __restrict__ wl0,
                                                   const float* __restrict__ wr0,
                                                   const float* __restrict__ wl1,
                                                   const float* __restrict__ wr1,
                                                   bf16_t* __restrict__ w0t,
                                                   bf16_t* __restrict__ w1t) {
    if ((int)blockIdx.x >= nbC) {
        // folded prep_w: transpose+concat both weight matrices to bf16
        int idx = (blockIdx.x - nbC) * 256 + threadIdx.x;
        if (idx < 128 * 128) {
            int j = idx >> 7, k = idx & 127;
            float v = (j < 64) ? wl0[k * 64 + j] : wr0[k * 64 + (j - 64)];
            w0t[idx] = (bf16_t)v;
        } else if (idx < 128 * 128 + 128 * 64) {
            int i2 = idx - 128 * 128;
            int j = i2 >> 6, k = i2 & 63;
            float v = (j < 64) ? wl1[k * 64 + j] : wr1[k * 64 + (j - 64)];
            w1t[i2] = (bf16_t)v;
        }
        return;
    }
    __shared__ int h[1024];
    for (int i = threadIdx.x; i < NB; i += 256) h[i] = 0;
    __syncthreads();
    int base = blockIdx.x * CHUNK;
#pragma unroll
    for (int k = 0; k < CHUNK / 256; ++k) {
        int e = base + threadIdx.x + k * 256;
        if (e < E) atomicAdd(&h[dstv[e] >> SHIFT], 1);
    }
    __syncthreads();
    for (int i = threadIdx.x; i < NB; i += 256)
        if (h[i]) atomicAdd(&bucket_cnt[i], h[i]);
}

// ---- pass A2: exclusive scan of bucket counts ----
__global__ __launch_bounds__(1024) void scan_bucket(const int* __restrict__ cnt,
                                                    int* __restrict__ boff,
                                                    int* __restrict__ bcur, int NB) {
    __shared__ int s[1024];
    int t = threadIdx.x;
    int v = (t < NB) ? cnt[t] : 0;
    s[t] = v;
    __syncthreads();
    for (int d = 1; d < 1024; d <<= 1) {
        int x = (t >= d) ? s[t - d] : 0;
        __syncthreads();
        s[t] += x;
        __syncthreads();
    }
    if (t < NB) {
        int o = s[t] - v;
        boff[t] = o;
        bcur[t] = o;
    }
    if (t == NB - 1) boff[NB] = s[t];
}

// ---- pass A3: LDS-staged bucket scatter ----
__global__ __launch_bounds__(256) void scatter_bucket(const int* __restrict__ srcv,
                                                      const int* __restrict__ dstv,
                                                      int* __restrict__ bcur,
                                                      int* __restrict__ bucketed,
                                                      int E, int NB) {
    __shared__ int hist[1024];
    __shared__ int offl[1024];
    __shared__ int basel[1024];
    __shared__ int partial[256];
    __shared__ int posA[CHUNK];
    __shared__ int valA[CHUNK];
    const int t = threadIdx.x;
    for (int i = t; i < NB; i += 256) hist[i] = 0;
    __syncthreads();

    const int cbase = blockIdx.x * CHUNK;
    int bk[CHUNK / 256], rk[CHUNK / 256], vv[CHUNK / 256];
#pragma unroll
    for (int k = 0; k < CHUNK / 256; ++k) {
        int e = cbase + t + k * 256;
        if (e < E) {
            int d = dstv[e];
            int s = srcv[e];
            int b = d >> SHIFT;
            bk[k] = b;
            rk[k] = atomicAdd(&hist[b], 1);
            vv[k] = (s << SHIFT) | (d & (BKT - 1));
        } else {
            bk[k] = -1;
        }
    }
    __syncthreads();

    for (int b = t; b < NB; b += 256) {
        int c = hist[b];
        basel[b] = c ? atomicAdd(&bcur[b], c) : 0;
    }
    {
        int g = t * 4;
        int a0 = (g + 0 < NB) ? hist[g + 0] : 0;
        int a1 = (g + 1 < NB) ? hist[g + 1] : 0;
        int a2 = (g + 2 < NB) ? hist[g + 2] : 0;
        int a3 = (g + 3 < NB) ? hist[g + 3] : 0;
        int sum = a0 + a1 + a2 + a3;
        partial[t] = sum;
        __syncthreads();
        for (int d = 1; d < 256; d <<= 1) {
            int x = (t >= d) ? partial[t - d] : 0;
            __syncthreads();
            partial[t] += x;
            __syncthreads();
        }
        int ex = partial[t] - sum;
        if (g + 0 < NB) offl[g + 0] = ex;
        if (g + 1 < NB) offl[g + 1] = ex + a0;
        if (g + 2 < NB) offl[g + 2] = ex + a0 + a1;
        if (g + 3 < NB) offl[g + 3] = ex + a0 + a1 + a2;
    }
    __syncthreads();

    int nloc = E - cbase;
    if (nloc > CHUNK) nloc = CHUNK;
#pragma unroll
    for (int k = 0; k < CHUNK / 256; ++k) {
        if (bk[k] >= 0) {
            int slot = offl[bk[k]] + rk[k];
            posA[slot] = basel[bk[k]] + rk[k];
            valA[slot] = vv[k];
        }
    }
    __syncthreads();
    for (int j = t; j < nloc; j += 256) bucketed[posA[j]] = valA[j];
}

// ---- pass B: per-bucket counting sort -> od{offs,deg}, csr ----
__global__ __launch_bounds__(256) void sort_bucket(const int* __restrict__ bucketed,
                                                   const int* __restrict__ boff,
                                                   int2* __restrict__ od,
                                                   int* __restrict__ csr, int N) {
    __shared__ int cnt[BKT];
    __shared__ int sc[BKT];
    __shared__ int cur[BKT];
    const int b = blockIdx.x;
    const int t = threadIdx.x;
    const int ebase = boff[b], eend = boff[b + 1];
    if (t < BKT) cnt[t] = 0;
    __syncthreads();
    for (int i = ebase + t; i < eend; i += 256)
        atomicAdd(&cnt[bucketed[i] & (BKT - 1)], 1);
    __syncthreads();
    int v = (t < BKT) ? cnt[t] : 0;
    if (t < BKT) sc[t] = v;
    __syncthreads();
    for (int d = 1; d < BKT; d <<= 1) {
        int x = (t < BKT && t >= d) ? sc[t - d] : 0;
        __syncthreads();
        if (t < BKT) sc[t] += x;
        __syncthreads();
    }
    if (t < BKT) {
        int ex = sc[t] - v;
        cur[t] = ex;
        int dst = (b << SHIFT) + t;
        if (dst < N) od[dst] = make_int2(ebase + ex, v);
    }
    __syncthreads();
    for (int i = ebase + t; i < eend; i += 256) {
        int w = bucketed[i];
        int p = atomicAdd(&cur[w & (BKT - 1)], 1);
        csr[ebase + p] = w >> SHIFT;
    }
}

// Y[N x 128] (bf16) = A[N x KTOT] @ W[KTOT x 128], via 16x16x32 bf16 MFMA.
template <int KTOT, bool AIN_BF16>
__global__ __launch_bounds__(256) void gemm_mfma(const void* __restrict__ Ain,
                                                 const bf16_t* __restrict__ Wt,
                                                 bf16_t* __restrict__ Y, int N) {
    const int lane = threadIdx.x & 63;
    const int wv = threadIdx.x >> 6;
    const int r0 = blockIdx.x * 64 + wv * 16;
    const int rr = lane & 15;
    const int quad = lane >> 4;
    const int row_store = r0 + rr;
    int row = (row_store < N) ? row_store : (N - 1);
    constexpr int NK = KTOT / 32;

    bf16x8 xf[NK];
    if (AIN_BF16) {
        const bf16_t* A = (const bf16_t*)Ain;
#pragma unroll
        for (int kk = 0; kk < NK; ++kk)
            xf[kk] = *(const bf16x8*)&A[(size_t)row * KTOT + kk * 32 + quad * 8];
    } else {
        const float* A = (const float*)Ain;
#pragma unroll
        for (int kk = 0; kk < NK; ++kk) {
            const float* ap = &A[(size_t)row * KTOT + kk * 32 + quad * 8];
            float4 f0 = *(const float4*)ap;
            float4 f1 = *(const float4*)(ap + 4);
            union { bf16x8 v; bf16_t h[8]; } u;
            u.h[0] = (bf16_t)f0.x; u.h[1] = (bf16_t)f0.y;
            u.h[2] = (bf16_t)f0.z; u.h[3] = (bf16_t)f0.w;
            u.h[4] = (bf16_t)f1.x; u.h[5] = (bf16_t)f1.y;
            u.h[6] = (bf16_t)f1.z; u.h[7] = (bf16_t)f1.w;
            xf[kk] = u.v;
        }
    }

#pragma unroll
    for (int c = 0; c < 8; ++c) {
        f32x4 acc = {0.f, 0.f, 0.f, 0.f};
#pragma unroll
        for (int kk = 0; kk < NK; ++kk) {
            bf16x8 wf = *(const bf16x8*)&Wt[(size_t)(c * 16 + rr) * KTOT + kk * 32 + quad * 8];
            acc = __builtin_amdgcn_mfma_f32_16x16x32_bf16(wf, xf[kk], acc, 0, 0, 0);
        }
        if (row_store < N) {
            union { bf16_t h[4]; uint2 u; } p;
            p.h[0] = (bf16_t)acc[0]; p.h[1] = (bf16_t)acc[1];
            p.h[2] = (bf16_t)acc[2]; p.h[3] = (bf16_t)acc[3];
            *(uint2*)&Y[(size_t)row_store * 128 + c * 16 + quad * 4] = p.u;
        }
    }
}

// agg_relu: one wave per node, two 32-lane halves (half h takes edges
// e==h mod 2); each half reads a 128 B bf16 message row as uint/lane.
// Edge indices from ONE coalesced csr load + __shfl under FULL exec;
// 8-pair unroll -> 8 independent y-gathers in flight before accumulation.
template <bool FUSED>
__global__ __launch_bounds__(256) void agg_relu(const bf16_t* __restrict__ y,
                                                const int* __restrict__ csr,
                                                const int2* __restrict__ od,
                                                const float* __restrict__ bias,
                                                bf16_t* __restrict__ h,
                                                const float* __restrict__ wl2,
                                                const float* __restrict__ wr2,
                                                float* __restrict__ sl,
                                                float* __restrict__ sr, int N) {
    int wid = blockIdx.x * 4 + (threadIdx.x >> 6);
    if (wid >= N) return;                    // wave-uniform
    const int lane = threadIdx.x & 63;
    const int half = lane >> 5;
    const int ch = (lane & 31) * 2;
    const int2 odv = od[wid];
    const int base = odv.x;
    const int d = odv.y;

    // one coalesced load: lane l holds src of edge l (l < min(d,64))
    int sidx = (lane < d) ? csr[base + lane] : 0;

    // last-edge index, resolved under FULL exec (divergent __shfl = UB)
    int lastLane = (d > 0 && d - 1 < 64) ? (d - 1) : 0;
    int s_last = __shfl(sidx, lastLane);

    float ax = 0.f, ay = 0.f;
    const int npairs = d >> 1;
    const int pm = (npairs < 32) ? npairs : 32;   // shfl-safe region (edge<64)
    int p = 0;
    for (; p + 8 <= pm; p += 8) {
        int s[8];
#pragma unroll
        for (int j = 0; j < 8; ++j) s[j] = __shfl(sidx, 2 * (p + j) + half);
        uint v[8];
#pragma unroll
        for (int j = 0; j < 8; ++j) v[j] = *(const uint*)&y[(size_t)s[j] * 128 + ch];
#pragma unroll
        for (int j = 0; j < 8; ++j) {
            ax += __uint_as_float(v[j] << 16);
            ay += __uint_as_float(v[j] & 0xffff0000u);
        }
    }
    for (; p < pm; ++p) {               // remaining pairs in shfl region
        int s0 = __shfl(sidx, 2 * p + half);
        uint v0 = *(const uint*)&y[(size_t)s0 * 128 + ch];
        ax += __uint_as_float(v0 << 16);
        ay += __uint_as_float(v0 & 0xffff0000u);
    }
    for (; p < npairs; ++p) {           // pairs beyond 64 edges: direct csr
        int s0 = csr[base + 2 * p + half];
        uint v0 = *(const uint*)&y[(size_t)s0 * 128 + ch];
        ax += __uint_as_float(v0 << 16);
        ay += __uint_as_float(v0 & 0xffff0000u);
    }
    if ((d & 1) && half == 0) {         // odd last edge, half 0 only
        int s0 = (d - 1 < 64) ? s_last : csr[base + d - 1];
        uint v0 = *(const uint*)&y[(size_t)s0 * 128 + ch];
        ax += __uint_as_float(v0 << 16);
        ay += __uint_as_float(v0 & 0xffff0000u);
    }
    ax += __shfl_xor(ax, 32);
    ay += __shfl_xor(ay, 32);

    float inv = 1.f / ((d > 0) ? (float)d : 1.f);
    uint vs = *(const uint*)&y[(size_t)wid * 128 + 64 + ch];
    float2 bv = *(const float2*)&bias[ch];
    float vx = fmaxf(ax * inv + __uint_as_float(vs << 16) + bv.x, 0.f);
    float vy = fmaxf(ay * inv + __uint_as_float(vs & 0xffff0000u) + bv.y, 0.f);

    if (!FUSED) {
        if (half == 0) {
            union { bf16_t b[2]; uint u; } pk;
            pk.b[0] = (bf16_t)vx;
            pk.b[1] = (bf16_t)vy;
            *(uint*)&h[(size_t)wid * 64 + ch] = pk.u;
        }
    } else {
        float a = vx * wl2[ch] + vy * wl2[ch + 1];
        float b = vx * wr2[ch] + vy * wr2[ch + 1];
#pragma unroll
        for (int off = 16; off; off >>= 1) {
            a += __shfl_xor(a, off);
            b += __shfl_xor(b, off);
        }
        if (lane == 0) {
            sl[wid] = a;
            sr[wid] = b;
        }
    }
}

// final: wave per node, lane-parallel sl gather + butterfly reduce + sigmoid
__global__ __launch_bounds__(256) void final_k(const float* __restrict__ sl,
                                               const float* __restrict__ sr,
                                               const int* __restrict__ csr,
                                               const int2* __restrict__ od,
                                               const float* __restrict__ b2,
                                               float* __restrict__ out, int N) {
    int wid = blockIdx.x * 4 + (threadIdx.x >> 6);
    if (wid >= N) return;
    const int lane = threadIdx.x & 63;
    const int2 odv = od[wid];
    const int base = odv.x;
    const int d = odv.y;
    float acc = 0.f;
    for (int e = lane; e < d; e += 64) acc += sl[csr[base + e]];
#pragma unroll
    for (int off = 32; off; off >>= 1) acc += __shfl_xor(acc, off);
    if (lane == 0) {
        float m = (d > 0) ? (float)d : 1.f;
        float v = acc / m + sr[wid] + b2[0];
        out[wid] = 1.f / (1.f + expf(-v));
    }
}

extern "C" void kernel_launch(void* const* d_in, const int* in_sizes, int n_in,
                              void* d_out, int out_size, void* d_ws, size_t ws_size,
                              hipStream_t stream) {
    const float* x  = (const float*)d_in[0];
    const int*  ei  = (const int*)d_in[1];
    const float* wl0 = (const float*)d_in[2];
    const float* wr0 = (const float*)d_in[3];
    const float* b0  = (const float*)d_in[4];
    const float* wl1 = (const float*)d_in[5];
    const float* wr1 = (const float*)d_in[6];
    const float* b1  = (const float*)d_in[7];
    const float* wl2 = (const float*)d_in[8];
    const float* wr2 = (const float*)d_in[9];
    const float* b2  = (const float*)d_in[10];
    float* out = (float*)d_out;

    const int E = in_sizes[1] / 2;
    const int N = out_size;
    const int* srcv = ei;
    const int* dstv = ei + E;
    const int NB = (N + BKT - 1) >> SHIFT;   // 782

    char* ws = (char*)d_ws;
    size_t o = 0;
    auto take = [&](size_t nbytes) -> void* {
        void* p = ws + o;
        o = (o + nbytes + 255) & ~(size_t)255;
        return p;
    };
    int2* od    = (int2*)take((size_t)N * 8);
    int* bcnt   = (int*)take((size_t)(NB + 2) * 4);
    int* boff   = (int*)take((size_t)(NB + 2) * 4);
    int* bcur   = (int*)take((size_t)(NB + 2) * 4);
    int* csr    = (int*)take((size_t)E * 4);
    bf16_t* w0t = (bf16_t*)take(128 * 128 * 2);
    bf16_t* w1t = (bf16_t*)take(128 * 64 * 2);
    bf16_t* y   = (bf16_t*)take((size_t)N * 128 * 2);
    bf16_t* h   = (bf16_t*)take((size_t)N * 64 * 2);
    float* sl   = (float*)take((size_t)N * 4);
    float* sr   = (float*)take((size_t)N * 4);
    int* bucketed = (int*)y;   // consumed by sort_bucket before gemm writes y
    (void)ws_size;

    const int nbC = (E + CHUNK - 1) / CHUNK;                 // 391
    const int nbP = (128 * 128 + 128 * 64 + 255) / 256;      // 96 prep blocks
    const int nbW = (N + 3) / 4;
    const int nbG = (N + 63) / 64;

    // CSR build (shared by all 3 layers)
    hipMemsetAsync(bcnt, 0, (size_t)NB * 4, stream);
    hist_bucket<<<nbC + nbP, 256, 0, stream>>>(dstv, bcnt, E, NB, nbC,
                                               wl0, wr0, wl1, wr1, w0t, w1t);
    scan_bucket<<<1, 1024, 0, stream>>>(bcnt, boff, bcur, NB);
    scatter_bucket<<<nbC, 256, 0, stream>>>(srcv, dstv, bcur, bucketed, E, NB);
    sort_bucket<<<NB, 256, 0, stream>>>(bucketed, boff, od, csr, N);

    // layer 0
    gemm_mfma<128, false><<<nbG, 256, 0, stream>>>((const void*)x, w0t, y, N);
    agg_relu<false><<<nbW, 256, 0, stream>>>(y, csr, od, b0, h,
                                             nullptr, nullptr, nullptr, nullptr, N);
    // layer 1 (fused with final-layer GEMV)
    gemm_mfma<64, true><<<nbG, 256, 0, stream>>>((const void*)h, w1t, y, N);
    agg_relu<true><<<nbW, 256, 0, stream>>>(y, csr, od, b1, nullptr,
                                            wl2, wr2, sl, sr, N);
    // final aggregation + sigmoid
    final_k<<<nbW, 256, 0, stream>>>(sl, sr, csr, od, b2, out, N);
}

// Round 8
// 314.471 us; speedup vs baseline: 1.0516x; 1.0516x over previous
//
#include <hip/hip_runtime.h>
#include <hip/hip_bf16.h>
#include <math.h>

// ---------------------------------------------------------------------------
// GraphSAGE (3-layer, mean aggr), N=100000, E=1600000.
// mean_agg(x) @ W == mean_agg(x @ W): GEMMs first, aggregate narrow messages.
// R7->R8: agg_relu made PERSISTENT (8192 waves grid-stride over nodes,
// prefetching next node's od+csr while current gathers are in flight — the
// per-node startup latency chain is paid once per wave, not once per node)
// and re-laid-out as lane=4 channels (uint2), quad=edge slot: one gather
// instruction covers 4 edges. All __shfl under full exec.
// CSR build via two-level counting sort (R2), weight prep folded into
// hist_bucket (R7).
// ---------------------------------------------------------------------------

#define SHIFT 7
#define BKT 128
#define CHUNK 4096

typedef __bf16 bf16_t;
typedef bf16_t bf16x8 __attribute__((ext_vector_type(8)));
typedef float f32x4 __attribute__((ext_vector_type(4)));

// ---- pass A1: histogram of dst>>SHIFT; extra blocks do the weight prep ----
__global__ __launch_bounds__(256) void hist_bucket(const int* __restrict__ dstv,
                                                   int* __restrict__ bucket_cnt,
                                                   int E, int NB, int nbC,
                                                   const float* __restrict__ wl0,
                                                   const float* __restrict__ wr0,
                                                   const float* __restrict__ wl1,
                                                   const float* __restrict__ wr1,
                                                   bf16_t* __restrict__ w0t,
                                                   bf16_t* __restrict__ w1t) {
    if ((int)blockIdx.x >= nbC) {
        int idx = (blockIdx.x - nbC) * 256 + threadIdx.x;
        if (idx < 128 * 128) {
            int j = idx >> 7, k = idx & 127;
            float v = (j < 64) ? wl0[k * 64 + j] : wr0[k * 64 + (j - 64)];
            w0t[idx] = (bf16_t)v;
        } else if (idx < 128 * 128 + 128 * 64) {
            int i2 = idx - 128 * 128;
            int j = i2 >> 6, k = i2 & 63;
            float v = (j < 64) ? wl1[k * 64 + j] : wr1[k * 64 + (j - 64)];
            w1t[i2] = (bf16_t)v;
        }
        return;
    }
    __shared__ int h[1024];
    for (int i = threadIdx.x; i < NB; i += 256) h[i] = 0;
    __syncthreads();
    int base = blockIdx.x * CHUNK;
#pragma unroll
    for (int k = 0; k < CHUNK / 256; ++k) {
        int e = base + threadIdx.x + k * 256;
        if (e < E) atomicAdd(&h[dstv[e] >> SHIFT], 1);
    }
    __syncthreads();
    for (int i = threadIdx.x; i < NB; i += 256)
        if (h[i]) atomicAdd(&bucket_cnt[i], h[i]);
}

// ---- pass A2: exclusive scan of bucket counts ----
__global__ __launch_bounds__(1024) void scan_bucket(const int* __restrict__ cnt,
                                                    int* __restrict__ boff,
                                                    int* __restrict__ bcur, int NB) {
    __shared__ int s[1024];
    int t = threadIdx.x;
    int v = (t < NB) ? cnt[t] : 0;
    s[t] = v;
    __syncthreads();
    for (int d = 1; d < 1024; d <<= 1) {
        int x = (t >= d) ? s[t - d] : 0;
        __syncthreads();
        s[t] += x;
        __syncthreads();
    }
    if (t < NB) {
        int o = s[t] - v;
        boff[t] = o;
        bcur[t] = o;
    }
    if (t == NB - 1) boff[NB] = s[t];
}

// ---- pass A3: LDS-staged bucket scatter ----
__global__ __launch_bounds__(256) void scatter_bucket(const int* __restrict__ srcv,
                                                      const int* __restrict__ dstv,
                                                      int* __restrict__ bcur,
                                                      int* __restrict__ bucketed,
                                                      int E, int NB) {
    __shared__ int hist[1024];
    __shared__ int offl[1024];
    __shared__ int basel[1024];
    __shared__ int partial[256];
    __shared__ int posA[CHUNK];
    __shared__ int valA[CHUNK];
    const int t = threadIdx.x;
    for (int i = t; i < NB; i += 256) hist[i] = 0;
    __syncthreads();

    const int cbase = blockIdx.x * CHUNK;
    int bk[CHUNK / 256], rk[CHUNK / 256], vv[CHUNK / 256];
#pragma unroll
    for (int k = 0; k < CHUNK / 256; ++k) {
        int e = cbase + t + k * 256;
        if (e < E) {
            int d = dstv[e];
            int s = srcv[e];
            int b = d >> SHIFT;
            bk[k] = b;
            rk[k] = atomicAdd(&hist[b], 1);
            vv[k] = (s << SHIFT) | (d & (BKT - 1));
        } else {
            bk[k] = -1;
        }
    }
    __syncthreads();

    for (int b = t; b < NB; b += 256) {
        int c = hist[b];
        basel[b] = c ? atomicAdd(&bcur[b], c) : 0;
    }
    {
        int g = t * 4;
        int a0 = (g + 0 < NB) ? hist[g + 0] : 0;
        int a1 = (g + 1 < NB) ? hist[g + 1] : 0;
        int a2 = (g + 2 < NB) ? hist[g + 2] : 0;
        int a3 = (g + 3 < NB) ? hist[g + 3] : 0;
        int sum = a0 + a1 + a2 + a3;
        partial[t] = sum;
        __syncthreads();
        for (int d = 1; d < 256; d <<= 1) {
            int x = (t >= d) ? partial[t - d] : 0;
            __syncthreads();
            partial[t] += x;
            __syncthreads();
        }
        int ex = partial[t] - sum;
        if (g + 0 < NB) offl[g + 0] = ex;
        if (g + 1 < NB) offl[g + 1] = ex + a0;
        if (g + 2 < NB) offl[g + 2] = ex + a0 + a1;
        if (g + 3 < NB) offl[g + 3] = ex + a0 + a1 + a2;
    }
    __syncthreads();

    int nloc = E - cbase;
    if (nloc > CHUNK) nloc = CHUNK;
#pragma unroll
    for (int k = 0; k < CHUNK / 256; ++k) {
        if (bk[k] >= 0) {
            int slot = offl[bk[k]] + rk[k];
            posA[slot] = basel[bk[k]] + rk[k];
            valA[slot] = vv[k];
        }
    }
    __syncthreads();
    for (int j = t; j < nloc; j += 256) bucketed[posA[j]] = valA[j];
}

// ---- pass B: per-bucket counting sort -> od{offs,deg}, csr ----
__global__ __launch_bounds__(256) void sort_bucket(const int* __restrict__ bucketed,
                                                   const int* __restrict__ boff,
                                                   int2* __restrict__ od,
                                                   int* __restrict__ csr, int N) {
    __shared__ int cnt[BKT];
    __shared__ int sc[BKT];
    __shared__ int cur[BKT];
    const int b = blockIdx.x;
    const int t = threadIdx.x;
    const int ebase = boff[b], eend = boff[b + 1];
    if (t < BKT) cnt[t] = 0;
    __syncthreads();
    for (int i = ebase + t; i < eend; i += 256)
        atomicAdd(&cnt[bucketed[i] & (BKT - 1)], 1);
    __syncthreads();
    int v = (t < BKT) ? cnt[t] : 0;
    if (t < BKT) sc[t] = v;
    __syncthreads();
    for (int d = 1; d < BKT; d <<= 1) {
        int x = (t < BKT && t >= d) ? sc[t - d] : 0;
        __syncthreads();
        if (t < BKT) sc[t] += x;
        __syncthreads();
    }
    if (t < BKT) {
        int ex = sc[t] - v;
        cur[t] = ex;
        int dst = (b << SHIFT) + t;
        if (dst < N) od[dst] = make_int2(ebase + ex, v);
    }
    __syncthreads();
    for (int i = ebase + t; i < eend; i += 256) {
        int w = bucketed[i];
        int p = atomicAdd(&cur[w & (BKT - 1)], 1);
        csr[ebase + p] = w >> SHIFT;
    }
}

// Y[N x 128] (bf16) = A[N x KTOT] @ W[KTOT x 128], via 16x16x32 bf16 MFMA.
template <int KTOT, bool AIN_BF16>
__global__ __launch_bounds__(256) void gemm_mfma(const void* __restrict__ Ain,
                                                 const bf16_t* __restrict__ Wt,
                                                 bf16_t* __restrict__ Y, int N) {
    const int lane = threadIdx.x & 63;
    const int wv = threadIdx.x >> 6;
    const int r0 = blockIdx.x * 64 + wv * 16;
    const int rr = lane & 15;
    const int quad = lane >> 4;
    const int row_store = r0 + rr;
    int row = (row_store < N) ? row_store : (N - 1);
    constexpr int NK = KTOT / 32;

    bf16x8 xf[NK];
    if (AIN_BF16) {
        const bf16_t* A = (const bf16_t*)Ain;
#pragma unroll
        for (int kk = 0; kk < NK; ++kk)
            xf[kk] = *(const bf16x8*)&A[(size_t)row * KTOT + kk * 32 + quad * 8];
    } else {
        const float* A = (const float*)Ain;
#pragma unroll
        for (int kk = 0; kk < NK; ++kk) {
            const float* ap = &A[(size_t)row * KTOT + kk * 32 + quad * 8];
            float4 f0 = *(const float4*)ap;
            float4 f1 = *(const float4*)(ap + 4);
            union { bf16x8 v; bf16_t h[8]; } u;
            u.h[0] = (bf16_t)f0.x; u.h[1] = (bf16_t)f0.y;
            u.h[2] = (bf16_t)f0.z; u.h[3] = (bf16_t)f0.w;
            u.h[4] = (bf16_t)f1.x; u.h[5] = (bf16_t)f1.y;
            u.h[6] = (bf16_t)f1.z; u.h[7] = (bf16_t)f1.w;
            xf[kk] = u.v;
        }
    }

#pragma unroll
    for (int c = 0; c < 8; ++c) {
        f32x4 acc = {0.f, 0.f, 0.f, 0.f};
#pragma unroll
        for (int kk = 0; kk < NK; ++kk) {
            bf16x8 wf = *(const bf16x8*)&Wt[(size_t)(c * 16 + rr) * KTOT + kk * 32 + quad * 8];
            acc = __builtin_amdgcn_mfma_f32_16x16x32_bf16(wf, xf[kk], acc, 0, 0, 0);
        }
        if (row_store < N) {
            union { bf16_t h[4]; uint2 u; } p;
            p.h[0] = (bf16_t)acc[0]; p.h[1] = (bf16_t)acc[1];
            p.h[2] = (bf16_t)acc[2]; p.h[3] = (bf16_t)acc[3];
            *(uint2*)&Y[(size_t)row_store * 128 + c * 16 + quad * 4] = p.u;
        }
    }
}

#define B16LO(u) __uint_as_float((u) << 16)
#define B16HI(u) __uint_as_float((u) & 0xffff0000u)

// agg_relu v4: PERSISTENT waves. Each wave grid-strides over nodes,
// prefetching next node's od+csr while current node's gathers are in
// flight. Lane layout: l16 = lane&15 -> 4 channels (uint2/lane),
// quad = lane>>4 -> edge slot (4 edges per gather instruction).
template <bool FUSED>
__global__ __launch_bounds__(256) void agg_relu(const bf16_t* __restrict__ y,
                                                const int* __restrict__ csr,
                                                const int2* __restrict__ od,
                                                const float* __restrict__ bias,
                                                bf16_t* __restrict__ h,
                                                const float* __restrict__ wl2,
                                                const float* __restrict__ wr2,
                                                float* __restrict__ sl,
                                                float* __restrict__ sr, int N) {
    const int lane = threadIdx.x & 63;
    const int quad = lane >> 4;
    const int ch = (lane & 15) * 4;
    const int nw = gridDim.x * 4;                 // total persistent waves

    int i = blockIdx.x * 4 + (threadIdx.x >> 6);
    int2 odc = (i < N) ? od[i] : make_int2(0, 0);
    int sidx = 0;
    if (i < N) sidx = (lane < odc.y) ? csr[odc.x + lane] : 0;

    while (i < N) {
        const int inext = i + nw;
        int2 odn = (inext < N) ? od[inext] : make_int2(0, 0);   // prefetch od

        const int base = odc.x;
        const int d = odc.y;
        float a0 = 0.f, a1 = 0.f, a2 = 0.f, a3 = 0.f;
        const int nblk = d >> 2;
        const int pm = (nblk < 16) ? nblk : 16;   // shfl-safe full blocks
        int p = 0;
        for (; p + 4 <= pm; p += 4) {
            int s0 = __shfl(sidx, 4 * p + quad);
            int s1 = __shfl(sidx, 4 * p + 4 + quad);
            int s2 = __shfl(sidx, 4 * p + 8 + quad);
            int s3 = __shfl(sidx, 4 * p + 12 + quad);
            uint2 v0 = *(const uint2*)&y[(size_t)s0 * 128 + ch];
            uint2 v1 = *(const uint2*)&y[(size_t)s1 * 128 + ch];
            uint2 v2 = *(const uint2*)&y[(size_t)s2 * 128 + ch];
            uint2 v3 = *(const uint2*)&y[(size_t)s3 * 128 + ch];
            a0 += B16LO(v0.x) + B16LO(v1.x) + B16LO(v2.x) + B16LO(v3.x);
            a1 += B16HI(v0.x) + B16HI(v1.x) + B16HI(v2.x) + B16HI(v3.x);
            a2 += B16LO(v0.y) + B16LO(v1.y) + B16LO(v2.y) + B16LO(v3.y);
            a3 += B16HI(v0.y) + B16HI(v1.y) + B16HI(v2.y) + B16HI(v3.y);
        }
        for (; p < pm; ++p) {
            int s0 = __shfl(sidx, 4 * p + quad);
            uint2 v0 = *(const uint2*)&y[(size_t)s0 * 128 + ch];
            a0 += B16LO(v0.x); a1 += B16HI(v0.x);
            a2 += B16LO(v0.y); a3 += B16HI(v0.y);
        }
        for (; p < nblk; ++p) {                   // edges >= 64: direct csr
            int s0 = csr[base + 4 * p + quad];
            uint2 v0 = *(const uint2*)&y[(size_t)s0 * 128 + ch];
            a0 += B16LO(v0.x); a1 += B16HI(v0.x);
            a2 += B16LO(v0.y); a3 += B16HI(v0.y);
        }
        // tail edges (d&3), shfl resolved under FULL exec w/ clamped index
        {
            int te = 4 * nblk + quad;
            int tec = (te < 64) ? te : 63;
            int s_t = __shfl(sidx, tec);
            if (te < d) {
                int s0 = (te < 64) ? s_t : csr[base + te];
                uint2 v0 = *(const uint2*)&y[(size_t)s0 * 128 + ch];
                a0 += B16LO(v0.x); a1 += B16HI(v0.x);
                a2 += B16LO(v0.y); a3 += B16HI(v0.y);
            }
        }

        // prefetch next node's csr while reductions run
        int sidxn = 0;
        if (inext < N) sidxn = (lane < odn.y) ? csr[odn.x + lane] : 0;

        // reduce across the 4 quads
        a0 += __shfl_xor(a0, 16); a1 += __shfl_xor(a1, 16);
        a2 += __shfl_xor(a2, 16); a3 += __shfl_xor(a3, 16);
        a0 += __shfl_xor(a0, 32); a1 += __shfl_xor(a1, 32);
        a2 += __shfl_xor(a2, 32); a3 += __shfl_xor(a3, 32);

        float inv = 1.f / ((d > 0) ? (float)d : 1.f);
        uint2 vs = *(const uint2*)&y[(size_t)i * 128 + 64 + ch];
        float4 bv = *(const float4*)&bias[ch];
        float vx0 = fmaxf(a0 * inv + B16LO(vs.x) + bv.x, 0.f);
        float vx1 = fmaxf(a1 * inv + B16HI(vs.x) + bv.y, 0.f);
        float vx2 = fmaxf(a2 * inv + B16LO(vs.y) + bv.z, 0.f);
        float vx3 = fmaxf(a3 * inv + B16HI(vs.y) + bv.w, 0.f);

        if (!FUSED) {
            if (quad == 0) {
                union { bf16_t b[4]; uint2 u; } pk;
                pk.b[0] = (bf16_t)vx0; pk.b[1] = (bf16_t)vx1;
                pk.b[2] = (bf16_t)vx2; pk.b[3] = (bf16_t)vx3;
                *(uint2*)&h[(size_t)i * 64 + ch] = pk.u;
            }
        } else {
            float4 wv = *(const float4*)&wl2[ch];
            float4 wu = *(const float4*)&wr2[ch];
            float a = vx0 * wv.x + vx1 * wv.y + vx2 * wv.z + vx3 * wv.w;
            float b = vx0 * wu.x + vx1 * wu.y + vx2 * wu.z + vx3 * wu.w;
#pragma unroll
            for (int off = 8; off; off >>= 1) {
                a += __shfl_xor(a, off);
                b += __shfl_xor(b, off);
            }
            if (lane == 0) {
                sl[i] = a;
                sr[i] = b;
            }
        }

        odc = odn;
        sidx = sidxn;
        i = inext;
    }
}

// final: wave per node, lane-parallel sl gather + butterfly reduce + sigmoid
__global__ __launch_bounds__(256) void final_k(const float* __restrict__ sl,
                                               const float* __restrict__ sr,
                                               const int* __restrict__ csr,
                                               const int2* __restrict__ od,
                                               const float* __restrict__ b2,
                                               float* __restrict__ out, int N) {
    int wid = blockIdx.x * 4 + (threadIdx.x >> 6);
    if (wid >= N) return;
    const int lane = threadIdx.x & 63;
    const int2 odv = od[wid];
    const int base = odv.x;
    const int d = odv.y;
    float acc = 0.f;
    for (int e = lane; e < d; e += 64) acc += sl[csr[base + e]];
#pragma unroll
    for (int off = 32; off; off >>= 1) acc += __shfl_xor(acc, off);
    if (lane == 0) {
        float m = (d > 0) ? (float)d : 1.f;
        float v = acc / m + sr[wid] + b2[0];
        out[wid] = 1.f / (1.f + expf(-v));
    }
}

extern "C" void kernel_launch(void* const* d_in, const int* in_sizes, int n_in,
                              void* d_out, int out_size, void* d_ws, size_t ws_size,
                              hipStream_t stream) {
    const float* x  = (const float*)d_in[0];
    const int*  ei  = (const int*)d_in[1];
    const float* wl0 = (const float*)d_in[2];
    const float* wr0 = (const float*)d_in[3];
    const float* b0  = (const float*)d_in[4];
    const float* wl1 = (const float*)d_in[5];
    const float* wr1 = (const float*)d_in[6];
    const float* b1  = (const float*)d_in[7];
    const float* wl2 = (const float*)d_in[8];
    const float* wr2 = (const float*)d_in[9];
    const float* b2  = (const float*)d_in[10];
    float* out = (float*)d_out;

    const int E = in_sizes[1] / 2;
    const int N = out_size;
    const int* srcv = ei;
    const int* dstv = ei + E;
    const int NB = (N + BKT - 1) >> SHIFT;   // 782

    char* ws = (char*)d_ws;
    size_t o = 0;
    auto take = [&](size_t nbytes) -> void* {
        void* p = ws + o;
        o = (o + nbytes + 255) & ~(size_t)255;
        return p;
    };
    int2* od    = (int2*)take((size_t)N * 8);
    int* bcnt   = (int*)take((size_t)(NB + 2) * 4);
    int* boff   = (int*)take((size_t)(NB + 2) * 4);
    int* bcur   = (int*)take((size_t)(NB + 2) * 4);
    int* csr    = (int*)take((size_t)E * 4);
    bf16_t* w0t = (bf16_t*)take(128 * 128 * 2);
    bf16_t* w1t = (bf16_t*)take(128 * 64 * 2);
    bf16_t* y   = (bf16_t*)take((size_t)N * 128 * 2);
    bf16_t* h   = (bf16_t*)take((size_t)N * 64 * 2);
    float* sl   = (float*)take((size_t)N * 4);
    float* sr   = (float*)take((size_t)N * 4);
    int* bucketed = (int*)y;   // consumed by sort_bucket before gemm writes y
    (void)ws_size;

    const int nbC = (E + CHUNK - 1) / CHUNK;                 // 391
    const int nbP = (128 * 128 + 128 * 64 + 255) / 256;      // 96 prep blocks
    const int nbW = (N + 3) / 4;
    const int nbG = (N + 63) / 64;
    const int nbA = 2048;                                    // persistent agg grid

    // CSR build (shared by all 3 layers)
    hipMemsetAsync(bcnt, 0, (size_t)NB * 4, stream);
    hist_bucket<<<nbC + nbP, 256, 0, stream>>>(dstv, bcnt, E, NB, nbC,
                                               wl0, wr0, wl1, wr1, w0t, w1t);
    scan_bucket<<<1, 1024, 0, stream>>>(bcnt, boff, bcur, NB);
    scatter_bucket<<<nbC, 256, 0, stream>>>(srcv, dstv, bcur, bucketed, E, NB);
    sort_bucket<<<NB, 256, 0, stream>>>(bucketed, boff, od, csr, N);

    // layer 0
    gemm_mfma<128, false><<<nbG, 256, 0, stream>>>((const void*)x, w0t, y, N);
    agg_relu<false><<<nbA, 256, 0, stream>>>(y, csr, od, b0, h,
                                             nullptr, nullptr, nullptr, nullptr, N);
    // layer 1 (fused with final-layer GEMV)
    gemm_mfma<64, true><<<nbG, 256, 0, stream>>>((const void*)h, w1t, y, N);
    agg_relu<true><<<nbA, 256, 0, stream>>>(y, csr, od, b1, nullptr,
                                            wl2, wr2, sl, sr, N);
    // final aggregation + sigmoid
    final_k<<<nbW, 256, 0, stream>>>(sl, sr, csr, od, b2, out, N);
}